// Round 1
// baseline (442.062 us; speedup 1.0000x reference)
//
#include <hip/hip_runtime.h>
#include <hip/hip_bf16.h>
#include <stdint.h>

#define N_NODES 10000
#define N_EDGES 100000
#define HIDDEN  128
#define MUL0    32
#define MUL1    8
#define IN_DIM  56
#define W_NUMEL 1600
#define NTILES  1563          // ceil(100000/64)
#define E_PAD   (NTILES*64)   // 100032

// ws layout (bytes)
#define OFF_BT1 0u             // 128x128 bf16 [n][k]
#define OFF_BT2 32768u         // 1600x128 bf16 [n][k]
#define OFF_H   442368u        // E_PAD x 128 bf16
#define OFF_NUM 26050560u      // 10000x56 f32
#define OFF_CNT 28290560u      // 10000 f32
#define OFF_SUM 28330560u      // 72 f32

typedef __attribute__((ext_vector_type(8))) short s8v;
typedef __attribute__((ext_vector_type(4))) float f4v;

__device__ __forceinline__ ushort f2b(float f) {
  uint32_t u = __float_as_uint(f);
  u += 0x7FFFu + ((u >> 16) & 1u);
  return (ushort)(u >> 16);
}

__global__ __launch_bounds__(256) void prep_kernel(
    const float* __restrict__ fc1_w, const float* __restrict__ fc2_w,
    ushort* __restrict__ Bt1, ushort* __restrict__ Bt2,
    float* __restrict__ num, float* __restrict__ cnt, float* __restrict__ sums) {
  int stride = gridDim.x * blockDim.x;
  int tid = blockIdx.x * blockDim.x + threadIdx.x;
  for (int i = tid; i < 128 * 128; i += stride) {
    int n = i >> 7, k = i & 127;
    Bt1[i] = f2b(fc1_w[k * 128 + n]);
  }
  for (int i = tid; i < 1600 * 128; i += stride) {
    int n = i >> 7, k = i & 127;
    Bt2[i] = f2b(fc2_w[k * 1600 + n]);
  }
  for (int i = tid; i < N_NODES * IN_DIM; i += stride) num[i] = 0.f;
  for (int i = tid; i < N_NODES; i += stride) cnt[i] = 0.f;
  for (int i = tid; i < 72; i += stride) sums[i] = 0.f;
}

// h = relu(edge_attr @ fc1_w + fc1_b), stored bf16 row-major [E_PAD][128]
__global__ __launch_bounds__(256) void gemm1_kernel(
    const float* __restrict__ edge_attr, const float* __restrict__ fc1_b,
    const ushort* __restrict__ Bt1, ushort* __restrict__ h) {
  __shared__ ushort sA[64 * 136];  // stride 136 bf16 (=272B) -> conflict-friendly b128 reads
  const int tid = threadIdx.x;
  const int e0 = blockIdx.x * 64;
  {
    int row = tid >> 2, cq = tid & 3;
    int e = e0 + row;
    ushort* dst = &sA[row * 136 + cq * 32];
    if (e < N_EDGES) {
      const float* src = edge_attr + (size_t)e * 128 + cq * 32;
#pragma unroll
      for (int i = 0; i < 8; ++i) {
        float4 v = *(const float4*)(src + i * 4);
        dst[i * 4 + 0] = f2b(v.x); dst[i * 4 + 1] = f2b(v.y);
        dst[i * 4 + 2] = f2b(v.z); dst[i * 4 + 3] = f2b(v.w);
      }
    } else {
#pragma unroll
      for (int i = 0; i < 32; ++i) dst[i] = 0;
    }
  }
  __syncthreads();
  const int wave = tid >> 6, lane = tid & 63, q = lane >> 4, m15 = lane & 15;
  f4v acc[4][2];
#pragma unroll
  for (int mb = 0; mb < 4; ++mb)
#pragma unroll
    for (int nb = 0; nb < 2; ++nb) acc[mb][nb] = (f4v){0.f, 0.f, 0.f, 0.f};
#pragma unroll
  for (int ki = 0; ki < 4; ++ki) {
    s8v a[4], b[2];
#pragma unroll
    for (int mb = 0; mb < 4; ++mb)
      a[mb] = *(const s8v*)&sA[(mb * 16 + m15) * 136 + ki * 32 + q * 8];
#pragma unroll
    for (int nb = 0; nb < 2; ++nb)
      b[nb] = *(const s8v*)&Bt1[(wave * 32 + nb * 16 + m15) * 128 + ki * 32 + q * 8];
#pragma unroll
    for (int mb = 0; mb < 4; ++mb) {
      acc[mb][0] = __builtin_amdgcn_mfma_f32_16x16x32_bf16(a[mb], b[0], acc[mb][0], 0, 0, 0);
      acc[mb][1] = __builtin_amdgcn_mfma_f32_16x16x32_bf16(a[mb], b[1], acc[mb][1], 0, 0, 0);
    }
  }
#pragma unroll
  for (int nb = 0; nb < 2; ++nb) {
    int col = wave * 32 + nb * 16 + m15;
    float bias = fc1_b[col];
#pragma unroll
    for (int mb = 0; mb < 4; ++mb)
#pragma unroll
      for (int r = 0; r < 4; ++r) {
        int row = mb * 16 + q * 4 + r;
        float v = fmaxf(acc[mb][nb][r] + bias, 0.f);
        h[(size_t)(e0 + row) * 128 + col] = f2b(v);
      }
  }
}

// fused: w = h@fc2_w + b (chunked, LDS-resident) -> TP contraction -> scatter-add
__global__ __launch_bounds__(256) void fused_kernel(
    const int* __restrict__ edge_index, const float* __restrict__ node_attr,
    const float* __restrict__ edge_sh, const float* __restrict__ fc2_b,
    const ushort* __restrict__ Bt2, const ushort* __restrict__ h,
    float* __restrict__ num, float* __restrict__ cnt) {
  __shared__ float wbuf[64 * 129];
  __shared__ float c0s[64][32];
  __shared__ float x0s[64][32];
  __shared__ float c1s[64][8];
  __shared__ float x1s[64][24];
  __shared__ float y0s[64];
  __shared__ float y1s[64][3];
  __shared__ int srcs[64];
  __shared__ int dsts[64];

  const int tid = threadIdx.x;
  const int e0 = blockIdx.x * 64;

  if (tid < 64) {
    int e = e0 + tid;
    if (e < N_EDGES) {
      srcs[tid] = edge_index[e];
      dsts[tid] = edge_index[N_EDGES + e];
      float4 sh = *(const float4*)(edge_sh + (size_t)e * 4);
      y0s[tid] = sh.x; y1s[tid][0] = sh.y; y1s[tid][1] = sh.z; y1s[tid][2] = sh.w;
    } else {
      srcs[tid] = -1; dsts[tid] = 0;
      y0s[tid] = 0.f; y1s[tid][0] = 0.f; y1s[tid][1] = 0.f; y1s[tid][2] = 0.f;
    }
  }
  __syncthreads();
  const int el = tid >> 2, r = tid & 3;
  {
    const float* xb = node_attr + (size_t)dsts[el] * IN_DIM;
    float y0 = y0s[el];
#pragma unroll
    for (int i = 0; i < 8; ++i) {
      int u = r * 8 + i;
      float v = xb[u];
      x0s[el][u] = v;
      c0s[el][u] = v * y0;
    }
#pragma unroll
    for (int i = 0; i < 6; ++i) {
      int idx = r * 6 + i;
      x1s[el][idx] = xb[32 + idx];
    }
  }
  __syncthreads();
  {
#pragma unroll
    for (int j = 0; j < 2; ++j) {
      int u = r * 2 + j;
      c1s[el][u] = 0.57735026919f * (x1s[el][u * 3 + 0] * y1s[el][0] +
                                     x1s[el][u * 3 + 1] * y1s[el][1] +
                                     x1s[el][u * 3 + 2] * y1s[el][2]);
    }
  }

  const int wave = tid >> 6, lane = tid & 63, q = lane >> 4, m15 = lane & 15;

  // resident A fragments: 64 edges x 128 K (bf16)
  s8v afrag[4][4];
#pragma unroll
  for (int mb = 0; mb < 4; ++mb)
#pragma unroll
    for (int ki = 0; ki < 4; ++ki)
      afrag[mb][ki] = *(const s8v*)&h[(size_t)(e0 + mb * 16 + m15) * 128 + ki * 32 + q * 8];

  float o0acc[8] = {0.f, 0.f, 0.f, 0.f, 0.f, 0.f, 0.f, 0.f};
  float aAcc[2] = {0.f, 0.f};
  float bAcc[6] = {0.f, 0.f, 0.f, 0.f, 0.f, 0.f};

  for (int ch = 0; ch < 13; ++ch) {
    const bool active = (ch < 12) || (wave < 2);
    f4v acc[4][2];
    if (active) {
#pragma unroll
      for (int mb = 0; mb < 4; ++mb)
#pragma unroll
        for (int nb = 0; nb < 2; ++nb) acc[mb][nb] = (f4v){0.f, 0.f, 0.f, 0.f};
      const int colbase = ch * 128 + wave * 32;
#pragma unroll
      for (int ki = 0; ki < 4; ++ki) {
        s8v b0 = *(const s8v*)&Bt2[(size_t)(colbase + m15) * 128 + ki * 32 + q * 8];
        s8v b1 = *(const s8v*)&Bt2[(size_t)(colbase + 16 + m15) * 128 + ki * 32 + q * 8];
#pragma unroll
        for (int mb = 0; mb < 4; ++mb) {
          acc[mb][0] = __builtin_amdgcn_mfma_f32_16x16x32_bf16(afrag[mb][ki], b0, acc[mb][0], 0, 0, 0);
          acc[mb][1] = __builtin_amdgcn_mfma_f32_16x16x32_bf16(afrag[mb][ki], b1, acc[mb][1], 0, 0, 0);
        }
      }
    }
    __syncthreads();  // previous contraction done reading wbuf
    if (active) {
#pragma unroll
      for (int nb = 0; nb < 2; ++nb) {
        int col_l = wave * 32 + nb * 16 + m15;
        float bias = fc2_b[ch * 128 + col_l];
#pragma unroll
        for (int mb = 0; mb < 4; ++mb)
#pragma unroll
          for (int rr = 0; rr < 4; ++rr)
            wbuf[(mb * 16 + q * 4 + rr) * 129 + col_l] = acc[mb][nb][rr] + bias;
      }
    }
    __syncthreads();  // wbuf ready
    const float* wrow = &wbuf[el * 129];
    if (ch < 8) {
#pragma unroll
      for (int u4 = 0; u4 < 4; ++u4) {
        float coef = c0s[el][ch * 4 + u4];
#pragma unroll
        for (int j = 0; j < 8; ++j) o0acc[j] += coef * wrow[u4 * 32 + r * 8 + j];
      }
    } else if (ch < 10) {
#pragma unroll
      for (int u4 = 0; u4 < 4; ++u4) {
        float coef = c1s[el][(ch - 8) * 4 + u4];
#pragma unroll
        for (int j = 0; j < 8; ++j) o0acc[j] += coef * wrow[u4 * 32 + r * 8 + j];
      }
    } else if (ch < 12) {
#pragma unroll
      for (int uu = 0; uu < 16; ++uu) {
        float coef = x0s[el][(ch - 10) * 16 + uu];
#pragma unroll
        for (int j = 0; j < 2; ++j) aAcc[j] += coef * wrow[uu * 8 + r * 2 + j];
      }
    } else {
#pragma unroll
      for (int u = 0; u < 8; ++u) {
#pragma unroll
        for (int j = 0; j < 2; ++j) {
          float wv = wrow[u * 8 + r * 2 + j];
#pragma unroll
          for (int m = 0; m < 3; ++m) bAcc[j * 3 + m] += x1s[el][u * 3 + m] * wv;
        }
      }
    }
  }

  // scatter
  int e = e0 + el;
  if (e < N_EDGES) {
    const float alpha = 0.15811388300841897f;
    int s = srcs[el];
    float* base = num + (size_t)s * IN_DIM;
#pragma unroll
    for (int j = 0; j < 8; ++j) atomicAdd(base + r * 8 + j, alpha * o0acc[j]);
    float y0 = y0s[el];
#pragma unroll
    for (int j = 0; j < 2; ++j) {
      int wp = r * 2 + j;
#pragma unroll
      for (int m = 0; m < 3; ++m) {
        float v = alpha * (y1s[el][m] * aAcc[j] + y0 * bAcc[j * 3 + m]);
        atomicAdd(base + 32 + wp * 3 + m, v);
      }
    }
    if (r == 0) atomicAdd(cnt + s, 1.0f);
  }
}

// out_pre = num/max(cnt,1) + node_attr; reduce column stats
__global__ __launch_bounds__(256) void bn_reduce_kernel(
    const float* __restrict__ num, const float* __restrict__ cnt,
    const float* __restrict__ node_attr, float* __restrict__ outp,
    float* __restrict__ sums) {
  int n = blockIdx.x * 256 + threadIdx.x;
  float vals[56];
  if (n < N_NODES) {
    float inv = 1.0f / fmaxf(cnt[n], 1.0f);
#pragma unroll
    for (int o = 0; o < 56; ++o) {
      float v = num[(size_t)n * 56 + o] * inv + node_attr[(size_t)n * 56 + o];
      vals[o] = v;
      outp[(size_t)n * 56 + o] = v;
    }
  } else {
#pragma unroll
    for (int o = 0; o < 56; ++o) vals[o] = 0.f;
  }
  int lane = threadIdx.x & 63;
#pragma unroll
  for (int o = 0; o < 32; ++o) {
    float a = vals[o], b = vals[o] * vals[o];
#pragma unroll
    for (int m = 1; m < 64; m <<= 1) { a += __shfl_xor(a, m); b += __shfl_xor(b, m); }
    if (lane == 0) { atomicAdd(&sums[o], a); atomicAdd(&sums[32 + o], b); }
  }
#pragma unroll
  for (int w = 0; w < 8; ++w) {
    float b = vals[32 + w * 3] * vals[32 + w * 3] +
              vals[32 + w * 3 + 1] * vals[32 + w * 3 + 1] +
              vals[32 + w * 3 + 2] * vals[32 + w * 3 + 2];
#pragma unroll
    for (int m = 1; m < 64; m <<= 1) b += __shfl_xor(b, m);
    if (lane == 0) atomicAdd(&sums[64 + w], b);
  }
}

__global__ __launch_bounds__(256) void bn_apply_kernel(
    float* __restrict__ outp, const float* __restrict__ sums,
    const float* __restrict__ bn_w_s, const float* __restrict__ bn_b_s,
    const float* __restrict__ bn_w_v) {
  int i = blockIdx.x * 256 + threadIdx.x;
  if (i >= N_NODES * IN_DIM) return;
  int o = i % 56;
  float v = outp[i];
  if (o < 32) {
    float mean = sums[o] * (1.0f / N_NODES);
    float var = sums[32 + o] * (1.0f / N_NODES) - mean * mean;
    v = (v - mean) * rsqrtf(var + 1e-5f) * bn_w_s[o] + bn_b_s[o];
  } else {
    int w = (o - 32) / 3;
    float vn = sums[64 + w] * (1.0f / (3 * N_NODES));
    v = v * rsqrtf(vn + 1e-5f) * bn_w_v[w];
  }
  outp[i] = v;
}

extern "C" void kernel_launch(void* const* d_in, const int* in_sizes, int n_in,
                              void* d_out, int out_size, void* d_ws, size_t ws_size,
                              hipStream_t stream) {
  const float* node_attr = (const float*)d_in[0];
  const int* edge_index  = (const int*)d_in[1];
  const float* edge_attr = (const float*)d_in[2];
  const float* edge_sh   = (const float*)d_in[3];
  const float* fc1_w     = (const float*)d_in[4];
  const float* fc1_b     = (const float*)d_in[5];
  const float* fc2_w     = (const float*)d_in[6];
  const float* fc2_b     = (const float*)d_in[7];
  const float* bn_w_s    = (const float*)d_in[8];
  const float* bn_w_v    = (const float*)d_in[9];
  const float* bn_b_s    = (const float*)d_in[10];

  char* ws = (char*)d_ws;
  ushort* Bt1 = (ushort*)(ws + OFF_BT1);
  ushort* Bt2 = (ushort*)(ws + OFF_BT2);
  ushort* h   = (ushort*)(ws + OFF_H);
  float* num  = (float*)(ws + OFF_NUM);
  float* cnt  = (float*)(ws + OFF_CNT);
  float* sums = (float*)(ws + OFF_SUM);
  float* outp = (float*)d_out;

  prep_kernel<<<512, 256, 0, stream>>>(fc1_w, fc2_w, Bt1, Bt2, num, cnt, sums);
  gemm1_kernel<<<NTILES, 256, 0, stream>>>(edge_attr, fc1_b, Bt1, h);
  fused_kernel<<<NTILES, 256, 0, stream>>>(edge_index, node_attr, edge_sh, fc2_b, Bt2, h, num, cnt);
  bn_reduce_kernel<<<(N_NODES + 255) / 256, 256, 0, stream>>>(num, cnt, node_attr, outp, sums);
  bn_apply_kernel<<<(N_NODES * IN_DIM + 255) / 256, 256, 0, stream>>>(outp, sums, bn_w_s, bn_b_s, bn_w_v);
}